// Round 9
// baseline (97.816 us; speedup 1.0000x reference)
//
#include <hip/hip_runtime.h>
#include <hip/hip_fp16.h>
#include <math.h>

#define BATCH    64
#define IN_CAPS  2048
#define IN_DIM   16
#define NUM_CAPS 32
#define DIM_CAPS 16
#define NROUTE   3
#define CAPS_EPS 1e-7f

#define JSPLIT   16   // j's per phase; hat-half = 64*16*2048*16*2B = 67 MB (L3-resident)

typedef unsigned short ushort_t;

// ---------------------------------------------------------------------------
// Kernel A: hat[b][jh][i][m] = sum_n W[i][j0+jh][n][m] * x[b][i][n]  (fp16)
// Processes j in [j0, j0+16). grid (128 i-groups, 16 jh); 4 waves; wave wv
// owns batches [16*wv, 16*wv+16). Lane caches W[i,j,:,m0..3] in 16 float4
// VGPRs via raw asm loads (not rematerializable). hat-half written to a
// 67 MB ws region that stays Infinity-Cache-resident (the point of JSPLIT).
// ---------------------------------------------------------------------------
__global__ __launch_bounds__(256) void caps_hat_kernel(
    const float* __restrict__ x, const float* __restrict__ W,
    ushort_t* __restrict__ hat, int j0)
{
  const int ig    = blockIdx.x;    // 0..127
  const int jh    = blockIdx.y;    // 0..15
  const int j     = j0 + jh;
  const int t     = threadIdx.x;
  const int wv    = t >> 6;        // wave 0..3 -> b-quarter
  const int l     = t & 63;
  const int i_loc = l >> 2;
  const int m0    = (l & 3) * 4;
  const int i     = ig * 16 + i_loc;

  float4 Wr[16];
  {
    const float* wbase = W + (((size_t)i * NUM_CAPS + j) * IN_DIM) * DIM_CAPS + m0;
#pragma unroll
    for (int n = 0; n < 16; ++n) {
      const float* a = wbase + n * DIM_CAPS;
      asm volatile("global_load_dwordx4 %0, %1, off"
                   : "=v"(Wr[n]) : "v"(a) : "memory");
    }
    asm volatile("s_waitcnt vmcnt(0)" ::: "memory");
  }

  const int b0 = wv * 16;
  const float* xrow = x + ((size_t)b0 * IN_CAPS + i) * IN_DIM;
  ushort_t* hbase =
      hat + ((((size_t)b0 * JSPLIT) + jh) * IN_CAPS + i) * DIM_CAPS + m0;

  const size_t xstride = (size_t)IN_CAPS * IN_DIM;               // per b
  const size_t hstride = (size_t)JSPLIT * IN_CAPS * DIM_CAPS;    // per b

#define DOT16(acc, xb)                                   \
  do {                                                   \
    _Pragma("unroll")                                    \
    for (int nb = 0; nb < 4; ++nb) {                     \
      const float4 xv = (xb)[nb];                        \
      acc.x = fmaf(Wr[4 * nb + 0].x, xv.x, acc.x);       \
      acc.y = fmaf(Wr[4 * nb + 0].y, xv.x, acc.y);       \
      acc.z = fmaf(Wr[4 * nb + 0].z, xv.x, acc.z);       \
      acc.w = fmaf(Wr[4 * nb + 0].w, xv.x, acc.w);       \
      acc.x = fmaf(Wr[4 * nb + 1].x, xv.y, acc.x);       \
      acc.y = fmaf(Wr[4 * nb + 1].y, xv.y, acc.y);       \
      acc.z = fmaf(Wr[4 * nb + 1].z, xv.y, acc.z);       \
      acc.w = fmaf(Wr[4 * nb + 1].w, xv.y, acc.w);       \
      acc.x = fmaf(Wr[4 * nb + 2].x, xv.z, acc.x);       \
      acc.y = fmaf(Wr[4 * nb + 2].y, xv.z, acc.y);       \
      acc.z = fmaf(Wr[4 * nb + 2].z, xv.z, acc.z);       \
      acc.w = fmaf(Wr[4 * nb + 2].w, xv.z, acc.w);       \
      acc.x = fmaf(Wr[4 * nb + 3].x, xv.w, acc.x);       \
      acc.y = fmaf(Wr[4 * nb + 3].y, xv.w, acc.y);       \
      acc.z = fmaf(Wr[4 * nb + 3].z, xv.w, acc.z);       \
      acc.w = fmaf(Wr[4 * nb + 3].w, xv.w, acc.w);       \
    }                                                    \
  } while (0)

#define LOADX(buf, bi)                                                  \
  do {                                                                  \
    const float* xr_ = xrow + (size_t)((bi) & 15) * xstride;            \
    _Pragma("unroll")                                                   \
    for (int k_ = 0; k_ < 4; ++k_)                                      \
      (buf)[k_] = *reinterpret_cast<const float4*>(xr_ + 4 * k_);       \
  } while (0)

#define PACKST(bi, acc)                                                 \
  do {                                                                  \
    ushort4 st_;                                                        \
    st_.x = __half_as_ushort(__float2half(acc.x));                      \
    st_.y = __half_as_ushort(__float2half(acc.y));                      \
    st_.z = __half_as_ushort(__float2half(acc.z));                      \
    st_.w = __half_as_ushort(__float2half(acc.w));                      \
    *reinterpret_cast<ushort4*>(hbase + (size_t)(bi) * hstride) = st_;  \
  } while (0)

  float4 P[4], Q[4];
  LOADX(P, 0);
  LOADX(Q, 1);

#pragma unroll 1
  for (int k = 0; k < 8; ++k) {
    const int bA = 2 * k;
    const int bB = 2 * k + 1;

    float4 accA = make_float4(0.f, 0.f, 0.f, 0.f);
    DOT16(accA, P);
    LOADX(P, bA + 2);            // reload P for iteration k+1 (wraps at end)
    PACKST(bA, accA);

    float4 accB = make_float4(0.f, 0.f, 0.f, 0.f);
    DOT16(accB, Q);
    LOADX(Q, bB + 2);
    PACKST(bB, accB);
  }
#undef DOT16
#undef LOADX
#undef PACKST
}

// ---------------------------------------------------------------------------
// Kernel B: 3-iteration routing for one (b, j0+jh); hat-half slice is
// L3-resident (just written by the matching A launch). hat in REGISTERS:
// 512 threads; chunk u = t + 512q (16B, coalesced). Pair (t, t^1) shares the
// 8 capsules i = (t>>1) + 256q; even lane holds m 0..7, odd lane m 8..15.
// Block reduction: split-butterfly (9 shfl for 8 values), m = f(lane bits).
// ---------------------------------------------------------------------------
__global__ __launch_bounds__(512) void caps_route_kernel(
    const ushort_t* __restrict__ hat, float* __restrict__ out, int j0)
{
  __shared__ float red[8][20];   // [wave][m(16) + E(1) + pad]
  __shared__ float outs[16];

  const int bid  = blockIdx.x;            // = b*JSPLIT + jh
  const int b    = bid >> 4;
  const int jh   = bid & (JSPLIT - 1);
  const int t    = threadIdx.x;
  const int lane = t & 63;
  const int wv   = t >> 6;
  const int mh   = t & 1;                 // m-half: 0 -> m 0..7, 1 -> m 8..15

  const ushort_t* base = hat + ((size_t)b * JSPLIT + jh) * (IN_CAPS * DIM_CAPS);

  uint4 g[8];
#pragma unroll
  for (int q = 0; q < 8; ++q)
    g[q] = *reinterpret_cast<const uint4*>(base + (size_t)(t + 512 * q) * 8);

  // H(q,s): fp16 value of hat[i_q][8*mh + s]
#define HVAL(q, s) __half2float(__ushort_as_half((ushort_t)( \
    ((s) & 1) ? (((const unsigned int*)&g[(q)])[(s) >> 1] >> 16) \
              : (((const unsigned int*)&g[(q)])[(s) >> 1] & 0xffffu))))

  const int b1 = (lane >> 1) & 1;
  const int b2 = (lane >> 2) & 1;
  const int b3 = (lane >> 3) & 1;
  // final m index this lane's butterfly result represents
  const int m_fin = 8 * mh + 4 * b3 + 2 * b2 + b1;

  float lg[8];
#pragma unroll
  for (int q = 0; q < 8; ++q) lg[q] = 0.f;

  for (int r = 0; r < NROUTE; ++r) {
    float e[8];
    float Ep = 0.f;
    if (r == 0) {
#pragma unroll
      for (int q = 0; q < 8; ++q) e[q] = 1.f;
    } else {
#pragma unroll
      for (int q = 0; q < 8; ++q) { e[q] = __expf(lg[q]); Ep += e[q]; }
    }

    // acc[s] = sum over my 8 i's of e_i * hat[i][8*mh+s]
    float acc[8];
#pragma unroll
    for (int s = 0; s < 8; ++s) {
      float a = 0.f;
#pragma unroll
      for (int q = 0; q < 8; ++q) a = fmaf(e[q], HVAL(q, s), a);
      acc[s] = a;
    }

    // ---- split-butterfly reduction over the wave (m-half already on bit0)
    float v4[4];
#pragma unroll
    for (int k = 0; k < 4; ++k) {               // xor 2  <-> s bit0
      float send = b1 ? acc[2 * k] : acc[2 * k + 1];
      float recv = __shfl_xor(send, 2);
      float keep = b1 ? acc[2 * k + 1] : acc[2 * k];
      v4[k] = keep + recv;                      // s = 2k + b1
    }
    float v2[2];
#pragma unroll
    for (int k = 0; k < 2; ++k) {               // xor 4  <-> s bit1
      float send = b2 ? v4[2 * k] : v4[2 * k + 1];
      float recv = __shfl_xor(send, 4);
      float keep = b2 ? v4[2 * k + 1] : v4[2 * k];
      v2[k] = keep + recv;                      // s = 4k + 2*b2 + b1
    }
    float z;
    {                                           // xor 8  <-> s bit2
      float send = b3 ? v2[0] : v2[1];
      float recv = __shfl_xor(send, 8);
      float keep = b3 ? v2[1] : v2[0];
      z = keep + recv;                          // s = 4*b3 + 2*b2 + b1
    }
    z += __shfl_xor(z, 16);
    z += __shfl_xor(z, 32);                     // summed over whole wave

    if (r > 0) {                                // E over wave: bits 1..5 only
      Ep += __shfl_xor(Ep, 2);
      Ep += __shfl_xor(Ep, 4);
      Ep += __shfl_xor(Ep, 8);
      Ep += __shfl_xor(Ep, 16);
      Ep += __shfl_xor(Ep, 32);
      if (lane == 16) red[wv][16] = Ep;
    }
    if (lane < 16) red[wv][m_fin] = z;
    __syncthreads();

    if (t < 16) {
      float s = 0.f;
#pragma unroll
      for (int w = 0; w < 8; ++w) s += red[w][t];
      float E;
      if (r == 0) E = (float)IN_CAPS;
      else {
        E = 0.f;
#pragma unroll
        for (int w = 0; w < 8; ++w) E += red[w][16];
      }
      float sm = s / E;
      float n2 = sm * sm;
#pragma unroll
      for (int off = 8; off >= 1; off >>= 1) n2 += __shfl_xor(n2, off);
      const float scale = n2 / (1.0f + n2) * rsqrtf(n2 + CAPS_EPS);
      const float o = scale * sm;
      outs[t] = o;
      if (r == NROUTE - 1)
        out[((size_t)b * NUM_CAPS + (j0 + jh)) * DIM_CAPS + t] = o;
    }
    __syncthreads();

    if (r < NROUTE - 1) {
      // logit update: lg_i += sum_m outs[m]*hat[i][m]; my half + partner half
#pragma unroll
      for (int q = 0; q < 8; ++q) {
        float d = 0.f;
#pragma unroll
        for (int s = 0; s < 8; ++s) d = fmaf(outs[8 * mh + s], HVAL(q, s), d);
        d += __shfl_xor(d, 1);                  // add partner's m-half
        lg[q] += d;
      }
    }
  }
#undef HVAL
}

extern "C" void kernel_launch(void* const* d_in, const int* in_sizes, int n_in,
                              void* d_out, int out_size, void* d_ws, size_t ws_size,
                              hipStream_t stream) {
  (void)in_sizes; (void)n_in; (void)out_size; (void)ws_size;
  const float* x = (const float*)d_in[0];      // [64][2048][16]
  const float* W = (const float*)d_in[1];      // [2048][32][16][16]
  float* outp = (float*)d_out;                 // [64][32][16]
  ushort_t* hat = (ushort_t*)d_ws;             // [64][JSPLIT][2048][16] fp16 = 67 MB, reused per phase

  for (int j0 = 0; j0 < NUM_CAPS; j0 += JSPLIT) {
    caps_hat_kernel<<<dim3(128, JSPLIT), dim3(256), 0, stream>>>(x, W, hat, j0);
    caps_route_kernel<<<dim3(BATCH * JSPLIT), dim3(512), 0, stream>>>(hat, outp, j0);
  }
}

// Round 10
// 84.183 us; speedup vs baseline: 1.1619x; 1.1619x over previous
//
#include <hip/hip_runtime.h>
#include <hip/hip_fp16.h>
#include <math.h>

#define BATCH    64
#define IN_CAPS  2048
#define IN_DIM   16
#define NUM_CAPS 32
#define DIM_CAPS 16
#define NROUTE   3
#define CAPS_EPS 1e-7f

typedef unsigned short ushort_t;

// ---------------------------------------------------------------------------
// Kernel A: hat[b][j][i][m] = sum_n W[i][j][n][m] * x[b][i][n]   (fp16 out)
// grid (128, 32) = (i-group, j); 256 threads = 4 waves; wave wv owns batches
// [16*wv, 16*wv+16). No LDS, no barriers. Lane holds W[i,j,:,m0..m0+3] in
// 16 float4 regs. This is R4's exact loop structure (plain runtime loop,
// conditional prefetch, xb/xn rotation, plain C loads) -- the ONLY variant
// where the compiler kept W register-resident (VGPR=132) -- combined with
// the 4096-block grid that R4 lacked.
// ---------------------------------------------------------------------------
__global__ __launch_bounds__(256) void caps_hat_kernel(
    const float* __restrict__ x, const float* __restrict__ W,
    ushort_t* __restrict__ hat)
{
  const int ig    = blockIdx.x;    // 0..127
  const int j     = blockIdx.y;    // 0..31
  const int t     = threadIdx.x;
  const int wv    = t >> 6;        // wave 0..3 -> b-quarter
  const int l     = t & 63;
  const int i_loc = l >> 2;
  const int m0    = (l & 3) * 4;
  const int i     = ig * 16 + i_loc;

  float4 Wr[16];
  {
    const float* wbase = W + (((size_t)i * NUM_CAPS + j) * IN_DIM) * DIM_CAPS + m0;
#pragma unroll
    for (int n = 0; n < 16; ++n)
      Wr[n] = *reinterpret_cast<const float4*>(wbase + n * DIM_CAPS);
  }

  const int b0 = wv * 16;
  const float* xrow = x + ((size_t)b0 * IN_CAPS + i) * IN_DIM;
  ushort_t* hbase =
      hat + ((((size_t)b0 * NUM_CAPS) + j) * IN_CAPS + i) * DIM_CAPS + m0;

  const size_t xstride = (size_t)IN_CAPS * IN_DIM;               // per b
  const size_t hstride = (size_t)NUM_CAPS * IN_CAPS * DIM_CAPS;  // per b

  float4 xb[4], xn[4];
#pragma unroll
  for (int k = 0; k < 4; ++k)
    xb[k] = *reinterpret_cast<const float4*>(xrow + 4 * k);

  for (int bi = 0; bi < 16; ++bi) {
    if (bi + 1 < 16) {
      const float* xr = xrow + (size_t)(bi + 1) * xstride;
#pragma unroll
      for (int k = 0; k < 4; ++k)
        xn[k] = *reinterpret_cast<const float4*>(xr + 4 * k);
    }
    float4 acc = make_float4(0.f, 0.f, 0.f, 0.f);
#pragma unroll
    for (int nb = 0; nb < 4; ++nb) {
      const float4 xv = xb[nb];
      acc.x = fmaf(Wr[4 * nb + 0].x, xv.x, acc.x);
      acc.y = fmaf(Wr[4 * nb + 0].y, xv.x, acc.y);
      acc.z = fmaf(Wr[4 * nb + 0].z, xv.x, acc.z);
      acc.w = fmaf(Wr[4 * nb + 0].w, xv.x, acc.w);
      acc.x = fmaf(Wr[4 * nb + 1].x, xv.y, acc.x);
      acc.y = fmaf(Wr[4 * nb + 1].y, xv.y, acc.y);
      acc.z = fmaf(Wr[4 * nb + 1].z, xv.y, acc.z);
      acc.w = fmaf(Wr[4 * nb + 1].w, xv.y, acc.w);
      acc.x = fmaf(Wr[4 * nb + 2].x, xv.z, acc.x);
      acc.y = fmaf(Wr[4 * nb + 2].y, xv.z, acc.y);
      acc.z = fmaf(Wr[4 * nb + 2].z, xv.z, acc.z);
      acc.w = fmaf(Wr[4 * nb + 2].w, xv.z, acc.w);
      acc.x = fmaf(Wr[4 * nb + 3].x, xv.w, acc.x);
      acc.y = fmaf(Wr[4 * nb + 3].y, xv.w, acc.y);
      acc.z = fmaf(Wr[4 * nb + 3].z, xv.w, acc.z);
      acc.w = fmaf(Wr[4 * nb + 3].w, xv.w, acc.w);
    }
    ushort4 st;
    st.x = __half_as_ushort(__float2half(acc.x));
    st.y = __half_as_ushort(__float2half(acc.y));
    st.z = __half_as_ushort(__float2half(acc.z));
    st.w = __half_as_ushort(__float2half(acc.w));
    *reinterpret_cast<ushort4*>(hbase + (size_t)bi * hstride) = st;
#pragma unroll
    for (int k = 0; k < 4; ++k) xb[k] = xn[k];
  }
}

// ---------------------------------------------------------------------------
// Kernel B: 3-iteration routing for one (b,j). hat slice held in REGISTERS:
// 512 threads; chunk u = t + 512q (16B, coalesced). Pair (t, t^1) shares the
// 8 capsules i = (t>>1) + 256q; even lane holds m 0..7, odd lane m 8..15.
// Block reduction: split-butterfly (9 shfl for 8 values), m = f(lane bits).
// ---------------------------------------------------------------------------
__global__ __launch_bounds__(512) void caps_route_kernel(
    const ushort_t* __restrict__ hat, float* __restrict__ out)
{
  __shared__ float red[8][20];   // [wave][m(16) + E(1) + pad]
  __shared__ float outs[16];

  const int bid  = blockIdx.x;            // = b*32 + j
  const int t    = threadIdx.x;
  const int lane = t & 63;
  const int wv   = t >> 6;
  const int mh   = t & 1;                 // m-half: 0 -> m 0..7, 1 -> m 8..15

  const ushort_t* base = hat + (size_t)bid * (IN_CAPS * DIM_CAPS);

  uint4 g[8];
#pragma unroll
  for (int q = 0; q < 8; ++q)
    g[q] = *reinterpret_cast<const uint4*>(base + (size_t)(t + 512 * q) * 8);

  // H(q,s): fp16 value of hat[i_q][8*mh + s]
#define HVAL(q, s) __half2float(__ushort_as_half((ushort_t)( \
    ((s) & 1) ? (((const unsigned int*)&g[(q)])[(s) >> 1] >> 16) \
              : (((const unsigned int*)&g[(q)])[(s) >> 1] & 0xffffu))))

  const int b1 = (lane >> 1) & 1;
  const int b2 = (lane >> 2) & 1;
  const int b3 = (lane >> 3) & 1;
  // final m index this lane's butterfly result represents
  const int m_fin = 8 * mh + 4 * b3 + 2 * b2 + b1;

  float lg[8];
#pragma unroll
  for (int q = 0; q < 8; ++q) lg[q] = 0.f;

  for (int r = 0; r < NROUTE; ++r) {
    float e[8];
    float Ep = 0.f;
    if (r == 0) {
#pragma unroll
      for (int q = 0; q < 8; ++q) e[q] = 1.f;
    } else {
#pragma unroll
      for (int q = 0; q < 8; ++q) { e[q] = __expf(lg[q]); Ep += e[q]; }
    }

    // acc[s] = sum over my 8 i's of e_i * hat[i][8*mh+s]
    float acc[8];
#pragma unroll
    for (int s = 0; s < 8; ++s) {
      float a = 0.f;
#pragma unroll
      for (int q = 0; q < 8; ++q) a = fmaf(e[q], HVAL(q, s), a);
      acc[s] = a;
    }

    // ---- split-butterfly reduction over the wave (m-half already on bit0)
    float v4[4];
#pragma unroll
    for (int k = 0; k < 4; ++k) {               // xor 2  <-> s bit0
      float send = b1 ? acc[2 * k] : acc[2 * k + 1];
      float recv = __shfl_xor(send, 2);
      float keep = b1 ? acc[2 * k + 1] : acc[2 * k];
      v4[k] = keep + recv;                      // s = 2k + b1
    }
    float v2[2];
#pragma unroll
    for (int k = 0; k < 2; ++k) {               // xor 4  <-> s bit1
      float send = b2 ? v4[2 * k] : v4[2 * k + 1];
      float recv = __shfl_xor(send, 4);
      float keep = b2 ? v4[2 * k + 1] : v4[2 * k];
      v2[k] = keep + recv;                      // s = 4k + 2*b2 + b1
    }
    float z;
    {                                           // xor 8  <-> s bit2
      float send = b3 ? v2[0] : v2[1];
      float recv = __shfl_xor(send, 8);
      float keep = b3 ? v2[1] : v2[0];
      z = keep + recv;                          // s = 4*b3 + 2*b2 + b1
    }
    z += __shfl_xor(z, 16);
    z += __shfl_xor(z, 32);                     // summed over whole wave

    if (r > 0) {                                // E over wave: bits 1..5 only
      Ep += __shfl_xor(Ep, 2);
      Ep += __shfl_xor(Ep, 4);
      Ep += __shfl_xor(Ep, 8);
      Ep += __shfl_xor(Ep, 16);
      Ep += __shfl_xor(Ep, 32);
      if (lane == 16) red[wv][16] = Ep;
    }
    if (lane < 16) red[wv][m_fin] = z;
    __syncthreads();

    if (t < 16) {
      float s = 0.f;
#pragma unroll
      for (int w = 0; w < 8; ++w) s += red[w][t];
      float E;
      if (r == 0) E = (float)IN_CAPS;
      else {
        E = 0.f;
#pragma unroll
        for (int w = 0; w < 8; ++w) E += red[w][16];
      }
      float sm = s / E;
      float n2 = sm * sm;
#pragma unroll
      for (int off = 8; off >= 1; off >>= 1) n2 += __shfl_xor(n2, off);
      const float scale = n2 / (1.0f + n2) * rsqrtf(n2 + CAPS_EPS);
      const float o = scale * sm;
      outs[t] = o;
      if (r == NROUTE - 1)
        out[(size_t)bid * DIM_CAPS + t] = o;
    }
    __syncthreads();

    if (r < NROUTE - 1) {
      // logit update: lg_i += sum_m outs[m]*hat[i][m]; my half + partner half
#pragma unroll
      for (int q = 0; q < 8; ++q) {
        float d = 0.f;
#pragma unroll
        for (int s = 0; s < 8; ++s) d = fmaf(outs[8 * mh + s], HVAL(q, s), d);
        d += __shfl_xor(d, 1);                  // add partner's m-half
        lg[q] += d;
      }
    }
  }
#undef HVAL
}

extern "C" void kernel_launch(void* const* d_in, const int* in_sizes, int n_in,
                              void* d_out, int out_size, void* d_ws, size_t ws_size,
                              hipStream_t stream) {
  (void)in_sizes; (void)n_in; (void)out_size; (void)ws_size;
  const float* x = (const float*)d_in[0];      // [64][2048][16]
  const float* W = (const float*)d_in[1];      // [2048][32][16][16]
  float* outp = (float*)d_out;                 // [64][32][16]
  ushort_t* hat = (ushort_t*)d_ws;             // [64][32][2048][16] fp16 = 134 MB

  caps_hat_kernel<<<dim3(128, 32), dim3(256), 0, stream>>>(x, W, hat);
  caps_route_kernel<<<dim3(BATCH * NUM_CAPS), dim3(512), 0, stream>>>(hat, outp);
}